// Round 10
// baseline (336.364 us; speedup 1.0000x reference)
//
#include <hip/hip_runtime.h>
#include <math.h>
#include <stdint.h>

#define LMAX 8
#define NPB 256   // points per tile, 1 thread per point (4 waves/block)

// Native clang vector type: __builtin_nontemporal_store rejects HIP's
// float4 (a HIP_vector_type class); it requires scalar or ext_vector types.
typedef float f32x4 __attribute__((ext_vector_type(4)));

// Host-computed coefficient pack, passed by value as a kernel arg.
// F[l][m] for m>=1: (-1)^m * sqrt((2l+1)/(2pi) * (l-m)!/(l+m)!)
// F[l][0]:          sqrt((2l+1)/(4pi))
// A[l][m] = (2l-1)/(l-m), B[l][m] = (l+m-1)/(l-m)
struct Coefs {
    float F[LMAX + 1][LMAX + 1];
    float A[LMAX + 1][LMAX + 1];
    float B[LMAX + 1][LMAX + 1];
};

// Evidence ledger (residual = dur_us minus the ~205us harness poison fill):
//   R0: 1-barrier, 41.5KB LDS,  6 waves/CU -> ~117us residual
//   R1: 9-barrier, 32KB LDS,   20 waves/CU -> ~118us residual (occupancy null)
//   R9: + nontemporal stores               -> ~124us residual (policy null)
// The rocclr fill hits 6.3 TB/s through the same L2 on the same buffer, so
// neither cache policy nor byte pattern (1024B-aligned full-line dwordx4)
// differentiates us. Remaining axis: execution modality -- fill is
// persistent waves issuing stores continuously; we were 3907 burst-and-die
// blocks (setup, ~20KB store burst per wave, teardown).
//
// R10 change: PERSISTENT GRID-STRIDE BLOCKS. 1024 blocks (4/CU), each loops
// over ~4 tiles. Store issue becomes continuous; block setup paid 1024x not
// 3907x; tile k+1's R-loads overlap tile k's store drain. One extra raw
// barrier per tile boundary protects bufA reuse (barrier count proven free).
__global__ __launch_bounds__(NPB, 4) void solid_harmonics_kernel(
    const float* __restrict__ R, float* __restrict__ out, int N, int ntiles,
    Coefs cf)
{
    __shared__ __align__(16) float bufA[NPB * 17];  // even l (max 2l+1 = 17)
    __shared__ __align__(16) float bufB[NPB * 15];  // odd  l (max 2l+1 = 15)

    const int t = threadIdx.x;

    for (int tile = blockIdx.x; tile < ntiles; tile += gridDim.x) {
        const int i0 = tile * NPB;
        const int i = i0 + t;
        const int rows = min(NPB, N - i0);

        // Tile-boundary barrier: previous tile's l=8 copy-out reads bufA
        // cross-thread; drain ds ops (lgkm only -- global stores stay in
        // flight) before overwriting bufA at l=0 below.
        asm volatile("s_waitcnt lgkmcnt(0)" ::: "memory");
        __builtin_amdgcn_sched_barrier(0);
        __builtin_amdgcn_s_barrier();
        __builtin_amdgcn_sched_barrier(0);

        float x = 0.f, y = 0.f, z = 0.f;
        if (i < N) {
            x = R[3 * i + 0];
            y = R[3 * i + 1];
            z = R[3 * i + 2];
        }
        const float r2 = x * x + y * y + z * z;

        // c[m] + i s[m] = (x+iy)^m, built incrementally.
        float c[LMAX + 1], s[LMAX + 1];
        c[0] = 1.f; s[0] = 0.f;

        // Rolling Q rows: Qcur = row l, Qm1 = row l-1, Qm2 = row l-2.
        float Qcur[LMAX + 1], Qm1[LMAX + 1], Qm2[LMAX + 1];
        Qcur[0] = 1.f;

#pragma unroll
        for (int l = 0; l <= LMAX; ++l) {
            if (l >= 1) {
#pragma unroll
                for (int m = 0; m < l - 1; ++m) Qm2[m] = Qm1[m];
#pragma unroll
                for (int m = 0; m < l; ++m) Qm1[m] = Qcur[m];
                c[l] = x * c[l - 1] - y * s[l - 1];
                s[l] = x * s[l - 1] + y * c[l - 1];
                Qcur[l]     = -(2.f * l - 1.f) * Qm1[l - 1];
                Qcur[l - 1] =  (2.f * l - 1.f) * z * Qm1[l - 1];
#pragma unroll
                for (int m = l - 2; m >= 0; --m)
                    Qcur[m] = cf.A[l][m] * z * Qm1[m] - cf.B[l][m] * r2 * Qm2[m];
            }

            const int stride = 2 * l + 1;
            float* buf = (l & 1) ? bufB : bufA;
            // Odd row stride -> <=2-way bank alias on scalar ds_writes (free).
            float* row = &buf[t * stride];
            row[l] = cf.F[l][0] * Qcur[0];
#pragma unroll
            for (int m = 1; m <= l; ++m) {
                const float fq = cf.F[l][m] * Qcur[m];
                row[l - m] = fq * s[m];
                row[l + m] = fq * c[m];
            }

            // All lanes' rows for this l staged. lgkm-only wait + raw
            // barrier: outstanding global stores stay in flight.
            asm volatile("s_waitcnt lgkmcnt(0)" ::: "memory");
            __builtin_amdgcn_sched_barrier(0);
            __builtin_amdgcn_s_barrier();
            __builtin_amdgcn_sched_barrier(0);

            // Cooperative coalesced copy-out of this tile's span for l.
            // Nontemporal (R9: null but harmless); output write-once > L3.
            float* obase = out + (size_t)N * (size_t)(l * l)
                               + (size_t)i0 * (size_t)stride;
            const int E = rows * stride;
            if (((E & 3) == 0) && ((((uintptr_t)obase) & 15u) == 0)) {
                const int E4 = E >> 2;
                const f32x4* s4 = (const f32x4*)buf;
                f32x4* o4 = (f32x4*)obase;
                for (int e = t; e < E4; e += NPB)
                    __builtin_nontemporal_store(s4[e], &o4[e]);
            } else {
                for (int e = t; e < E; e += NPB)
                    __builtin_nontemporal_store(buf[e], &obase[e]);
            }
            // No trailing barrier: next phase writes the OTHER buffer; the
            // next pre-barrier lgkmcnt(0) ordering protects this one.
        }
    }
}

extern "C" void kernel_launch(void* const* d_in, const int* in_sizes, int n_in,
                              void* d_out, int out_size, void* d_ws, size_t ws_size,
                              hipStream_t stream) {
    const float* R = (const float*)d_in[0];
    float* out = (float*)d_out;
    const int N = in_sizes[0] / 3;

    Coefs cf;
    double fact[2 * LMAX + 1];
    fact[0] = 1.0;
    for (int k = 1; k <= 2 * LMAX; ++k) fact[k] = fact[k - 1] * (double)k;
    const double PI = 3.14159265358979323846;
    for (int l = 0; l <= LMAX; ++l) {
        for (int m = 0; m <= LMAX; ++m) { cf.F[l][m] = 0.f; cf.A[l][m] = 0.f; cf.B[l][m] = 0.f; }
        cf.F[l][0] = (float)sqrt((2.0 * l + 1.0) / (4.0 * PI));
        for (int m = 1; m <= l; ++m) {
            double sign = (m & 1) ? -1.0 : 1.0;
            cf.F[l][m] = (float)(sign * sqrt((2.0 * l + 1.0) / (2.0 * PI)
                                             * fact[l - m] / fact[l + m]));
        }
        for (int m = 0; m <= l - 2; ++m) {
            cf.A[l][m] = (float)((2.0 * l - 1.0) / (double)(l - m));
            cf.B[l][m] = (float)((double)(l + m - 1) / (double)(l - m));
        }
    }

    const int ntiles = (N + NPB - 1) / NPB;
    const int grid = ntiles < 1024 ? ntiles : 1024;  // 4 blocks/CU, persistent
    solid_harmonics_kernel<<<grid, NPB, 0, stream>>>(R, out, N, ntiles, cf);
}

// Round 13
// 328.640 us; speedup vs baseline: 1.0235x; 1.0235x over previous
//
#include <hip/hip_runtime.h>
#include <math.h>
#include <stdint.h>

#define LMAX 8
#define NPB 256   // points per block, 1 thread per point (4 waves)

// Host-computed coefficient pack, passed by value as a kernel arg.
struct Coefs {
    float F[LMAX + 1][LMAX + 1];
    float A[LMAX + 1][LMAX + 1];
    float B[LMAX + 1][LMAX + 1];
};

// ===================== R11: DOUBLE-WRITE ABLATION =====================
// Purpose: measure the kernel's write-phase time directly from dur_us.
// Evidence so far: R0 (6 waves/CU) and R1 (20 waves/CU) agree to 0.1us;
// nt stores (R9) and persistent blocks (R10) null/regression. Suspect the
// ~117us "residual" over the 210us poison fill contains a large invariant
// harness component (dozens of tiny reset dispatches, per rocprof.md),
// masking a kernel that may already be write-BW-bound (~55us).
// Instrument: copy-out executed TWICE (identical data, identical addresses;
// asm memory clobber between passes prevents dead-store elimination).
// Correctness unchanged. delta(dur_us) vs R1's 327.5 = true write time.
//   delta ~= +55-65  -> kernel near roofline; restore R1 and declare.
//   delta ~= +110-120 -> write path truly ~2.8 TB/s; keep optimizing.
// ======================================================================
__global__ __launch_bounds__(NPB, 4) void solid_harmonics_kernel(
    const float* __restrict__ R, float* __restrict__ out, int N, Coefs cf)
{
    __shared__ __align__(16) float bufA[NPB * 17];  // even l (max 2l+1 = 17)
    __shared__ __align__(16) float bufB[NPB * 15];  // odd  l (max 2l+1 = 15)

    const int t = threadIdx.x;
    const int i0 = blockIdx.x * NPB;
    const int i = i0 + t;
    const int rows = min(NPB, N - i0);

    float x = 0.f, y = 0.f, z = 0.f;
    if (i < N) {
        x = R[3 * i + 0];
        y = R[3 * i + 1];
        z = R[3 * i + 2];
    }
    const float r2 = x * x + y * y + z * z;

    float c[LMAX + 1], s[LMAX + 1];
    c[0] = 1.f; s[0] = 0.f;

    float Qcur[LMAX + 1], Qm1[LMAX + 1], Qm2[LMAX + 1];
    Qcur[0] = 1.f;

#pragma unroll
    for (int l = 0; l <= LMAX; ++l) {
        if (l >= 1) {
#pragma unroll
            for (int m = 0; m < l - 1; ++m) Qm2[m] = Qm1[m];
#pragma unroll
            for (int m = 0; m < l; ++m) Qm1[m] = Qcur[m];
            c[l] = x * c[l - 1] - y * s[l - 1];
            s[l] = x * s[l - 1] + y * c[l - 1];
            Qcur[l]     = -(2.f * l - 1.f) * Qm1[l - 1];
            Qcur[l - 1] =  (2.f * l - 1.f) * z * Qm1[l - 1];
#pragma unroll
            for (int m = l - 2; m >= 0; --m)
                Qcur[m] = cf.A[l][m] * z * Qm1[m] - cf.B[l][m] * r2 * Qm2[m];
        }

        const int stride = 2 * l + 1;
        float* buf = (l & 1) ? bufB : bufA;
        float* row = &buf[t * stride];
        row[l] = cf.F[l][0] * Qcur[0];
#pragma unroll
        for (int m = 1; m <= l; ++m) {
            const float fq = cf.F[l][m] * Qcur[m];
            row[l - m] = fq * s[m];
            row[l + m] = fq * c[m];
        }

        // lgkm-only wait + raw barrier: global stores stay in flight.
        asm volatile("s_waitcnt lgkmcnt(0)" ::: "memory");
        __builtin_amdgcn_sched_barrier(0);
        __builtin_amdgcn_s_barrier();
        __builtin_amdgcn_sched_barrier(0);

        float* obase = out + (size_t)N * (size_t)(l * l) + (size_t)i0 * (size_t)stride;
        const int E = rows * stride;
        if (((E & 3) == 0) && ((((uintptr_t)obase) & 15u) == 0)) {
            const int E4 = E >> 2;
            const float4* s4 = (const float4*)buf;
            float4* o4 = (float4*)obase;
            // Pass 1
            for (int e = t; e < E4; e += NPB) o4[e] = s4[e];
            // DSE fence: compiler must assume the asm reads memory, so the
            // pass-1 stores cannot be eliminated as dead.
            asm volatile("" ::: "memory");
            // Pass 2 (ablation): identical data to identical addresses.
            for (int e = t; e < E4; e += NPB) o4[e] = s4[e];
        } else {
            for (int e = t; e < E; e += NPB) obase[e] = buf[e];
            asm volatile("" ::: "memory");
            for (int e = t; e < E; e += NPB) obase[e] = buf[e];
        }
        // No trailing barrier: next iteration writes the OTHER buffer,
        // and its pre-barrier lgkmcnt(0) ordering protects this one.
    }
}

extern "C" void kernel_launch(void* const* d_in, const int* in_sizes, int n_in,
                              void* d_out, int out_size, void* d_ws, size_t ws_size,
                              hipStream_t stream) {
    const float* R = (const float*)d_in[0];
    float* out = (float*)d_out;
    const int N = in_sizes[0] / 3;

    Coefs cf;
    double fact[2 * LMAX + 1];
    fact[0] = 1.0;
    for (int k = 1; k <= 2 * LMAX; ++k) fact[k] = fact[k - 1] * (double)k;
    const double PI = 3.14159265358979323846;
    for (int l = 0; l <= LMAX; ++l) {
        for (int m = 0; m <= LMAX; ++m) { cf.F[l][m] = 0.f; cf.A[l][m] = 0.f; cf.B[l][m] = 0.f; }
        cf.F[l][0] = (float)sqrt((2.0 * l + 1.0) / (4.0 * PI));
        for (int m = 1; m <= l; ++m) {
            double sign = (m & 1) ? -1.0 : 1.0;
            cf.F[l][m] = (float)(sign * sqrt((2.0 * l + 1.0) / (2.0 * PI)
                                             * fact[l - m] / fact[l + m]));
        }
        for (int m = 0; m <= l - 2; ++m) {
            cf.A[l][m] = (float)((2.0 * l - 1.0) / (double)(l - m));
            cf.B[l][m] = (float)((double)(l + m - 1) / (double)(l - m));
        }
    }

    const int grid = (N + NPB - 1) / NPB;
    solid_harmonics_kernel<<<grid, NPB, 0, stream>>>(R, out, N, cf);
}